// Round 8
// baseline (266.062 us; speedup 1.0000x reference)
//
#include <hip/hip_runtime.h>
#include <hip/hip_bf16.h>

// ---------------------------------------------------------------------------
// Pipelined MFMA LSTM (B=8192,T=200,IN=4,H=16) + fused MLP (3200->64->28).
//   - block = 4 waves = one 16-sample group; wave l owns layer l AND MLP tile l
//   - software pipeline over timestep QUADS: superstep n, wave l computes
//     t = 4(n-l)..4(n-l)+3; ONE barrier per 4 timesteps (54 total)
//   - h stored in LDS as PRE-SPLIT bf16 hi/lo, INTERLEAVED per sample row:
//     [hi j0-7 | hi j8-15 | lo j0-7 | lo j8-15 | pad] (80B stride)
//   - ALL LDS addresses hoisted: 6 base regs computed once (the only lane-
//     dependent select q<2 vs q>=2 is one cndmask at start); every in-loop
//     ds access is base + compile-time immediate (superstep body instantiated
//     per parity via lambda, st fully unrolled)
//   - W1 (pre-split bf16 planes in d_ws) loaded at TOP of the superstep that
//     consumes it: 4 recurrent steps cover the L2-hit latency; no reg rotation
//   - per layer: G[64,32] = [Wih|Whh] @ [h_{l-1};h_l] via mfma_f32_16x16x32_bf16
//     (3-term trunc hi/lo bf16 split, fp32-grade; bit-identical to R7)
// ---------------------------------------------------------------------------

typedef short  bf16x8 __attribute__((ext_vector_type(8)));
typedef float  f32x4  __attribute__((ext_vector_type(4)));
typedef unsigned int uint2v __attribute__((ext_vector_type(2)));

namespace {
constexpr int kT    = 200;
constexpr int kOut  = 28;
constexpr int kQ    = kT / 4;          // 50 quads
constexpr int kSteps = kQ + 4;         // 54 (even)
constexpr float kNLog2e  = -1.4426950408889634f;   // -log2(e)
constexpr float kN2Log2e = -2.8853900817779268f;   // -2*log2(e)
constexpr int kW1Elems = 64 * 3200;
// H geometry (ushort units)
constexpr int kRow  = 40;              // per-sample row: hi8|hi8|lo8|lo8|pad8
constexpr int kSlot = 16 * kRow;       // 640
constexpr int kLay  = 4 * kSlot;       // 2560
constexpr int kPar  = 4 * kLay;        // 10240
}

union FragU { bf16x8 v; unsigned u[4]; };

__device__ __forceinline__ float fast_rcp(float v){ return __builtin_amdgcn_rcpf(v); }
__device__ __forceinline__ float fast_exp2(float v){ return __builtin_amdgcn_exp2f(v); }
// input already scaled by -log2e (folded into weights+bias)
__device__ __forceinline__ float sig_scaled(float p){ return fast_rcp(1.0f + fast_exp2(p)); }
__device__ __forceinline__ float tanh_true(float v){
  return fmaf(fast_rcp(1.0f + fast_exp2(kN2Log2e*v)), 2.0f, -1.0f);
}

// trunc-split 8 f32 -> bf16 hi frag + bf16 lo frag
__device__ __forceinline__ void split8(const float* v, FragU& hi, FragU& lo){
#pragma unroll
  for (int r=0;r<4;++r){
    unsigned ua=__float_as_uint(v[2*r]), ub=__float_as_uint(v[2*r+1]);
    hi.u[r] = (ua>>16) | (ub & 0xffff0000u);
    float af=__uint_as_float(ua & 0xffff0000u);
    float bf=__uint_as_float(ub & 0xffff0000u);
    float al=v[2*r]-af, bl=v[2*r+1]-bf;
    lo.u[r] = (__float_as_uint(al)>>16) | (__float_as_uint(bl) & 0xffff0000u);
  }
}

__global__ __launch_bounds__(256)
void presplit_w1(const float* __restrict__ W1,
                 short* __restrict__ W1h, short* __restrict__ W1l){
  int i = blockIdx.x*256 + threadIdx.x;
  if (i < kW1Elems){
    float v = W1[i];
    unsigned u = __float_as_uint(v);
    float hif = __uint_as_float(u & 0xffff0000u);
    float lo  = v - hif;
    W1h[i] = (short)(u >> 16);
    W1l[i] = (short)(__float_as_uint(lo) >> 16);
  }
}

template<bool PS>
__global__ __launch_bounds__(256)
void lstm_pipe(const float* __restrict__ x,     // [B,T,4]
               const float* __restrict__ Wih0,  // [64,4]
               const float* __restrict__ Wihr,  // [3,64,16]
               const float* __restrict__ Whh,   // [4,64,16]
               const float* __restrict__ bih,   // [4,64]
               const float* __restrict__ bhh,   // [4,64]
               const float* __restrict__ W1,    // [64,3200]
               const float* __restrict__ b1,    // [64]
               const float* __restrict__ W2,    // [28,64]
               const float* __restrict__ b2,    // [28]
               const short* __restrict__ W1h,   // [64,3200] bf16 hi plane
               const short* __restrict__ W1l,   // [64,3200] bf16 lo plane
               float* __restrict__ out)         // [B,28]
{
  __shared__ unsigned short H[2*kPar];   // packed h (hi/lo interleaved rows)
  __shared__ float ldsR[16][68];         // relu(hid), padded

  const int tid  = threadIdx.x;
  const int lane = tid & 63;
  const int wv   = tid >> 6;            // 0..3: layer index AND mlp tile index
  const int s    = lane & 15;           // sample within group (= MFMA col)
  const int q    = lane >> 4;           // lane quadrant (= k-chunk / row group)
  const int l    = wv;
  const int lm1  = (l==0) ? 0 : (l-1);
  const int sbase = blockIdx.x * 16;

  for (int i = tid; i < 2*kPar/2; i += 256) ((unsigned*)H)[i] = 0u;

  // ---- A fragments for THIS wave's layer: row=lane&15, k=q*8+e, tile=gate
  FragU A[4][2];
#pragma unroll
  for (int tile=0;tile<4;++tile){
    const int grow = tile*16 + s;
    const float kE = (tile==2)? kN2Log2e : kNLog2e;
    float v[8];
    if (l==0){
#pragma unroll
      for (int e=0;e<8;++e){
        float w = 0.f;
        if (q==0 && e<4) w = Wih0[grow*4+e];
        if (q>=2)        w = Whh[grow*16 + (q&1)*8 + e];
        v[e] = w*kE;
      }
    } else {
#pragma unroll
      for (int e=0;e<8;++e){
        float w = (q<2) ? Wihr[((l-1)*64+grow)*16 + q*8 + e]
                        : Whh [(( l )*64+grow)*16 + (q&1)*8 + e];
        v[e] = w*kE;
      }
    }
    split8(v, A[tile][0], A[tile][1]);
  }

  // ---- scaled bias in VGPRs (C-init)
  f32x4 biasf[4];
#pragma unroll
  for (int tile=0;tile<4;++tile){
    const float kE = (tile==2)? kN2Log2e : kNLog2e;
#pragma unroll
    for (int r=0;r<4;++r){
      const int row = l*64 + tile*16 + 4*q + r;
      biasf[tile][r] = (bih[row] + bhh[row]) * kE;
    }
  }

  float cst[4] = {0.f,0.f,0.f,0.f};
  f32x4 mlpacc = (f32x4){0.f,0.f,0.f,0.f};

  const float* xp = x + (size_t)(sbase+s)*(kT*4);
  float4 xc0,xc1,xc2,xc3;               // current quad's x (wave 0)
  if (l==0){
    xc0 = *(const float4*)(xp+ 0); xc1 = *(const float4*)(xp+ 4);
    xc2 = *(const float4*)(xp+ 8); xc3 = *(const float4*)(xp+12);
  }

  const int rowW1 = wv*16 + s;
  const short* w1hp = W1h + (size_t)rowW1*3200;
  const short* w1lp = W1l + (size_t)rowW1*3200;
  const float* w1fp = W1  + (size_t)rowW1*3200;

  // ---- hoisted LDS base addresses (ushort units; per-access = base + imm)
  const int laneRd = s*kRow + (q&1)*8;
  const int laneWr = s*kRow + q*4;
  auto OFF = [](int par,int layer,int slot){ return par*kPar + layer*kLay + slot*kSlot; };
  // parity 0 body (p=0): reads prev parity 1; writes parity 0
  const unsigned short* ra0_0 = H + laneRd + ((q<2) ? OFF(1,lm1,0) : OFF(1,l,3));
  const unsigned short* raS_0 = H + laneRd + ((q<2) ? OFF(1,lm1,1) : OFF(0,l,0));
  unsigned short*       wrt_0 = H + laneWr + OFF(0,l,0);
  const unsigned short* mrd_0 = H + laneRd + OFF(1,3,0) + (q>>1)*kSlot;
  // parity 1 body (p=1): reads prev parity 0; writes parity 1
  const unsigned short* ra0_1 = H + laneRd + ((q<2) ? OFF(0,lm1,0) : OFF(0,l,3));
  const unsigned short* raS_1 = H + laneRd + ((q<2) ? OFF(0,lm1,1) : OFF(1,l,0));
  unsigned short*       wrt_1 = H + laneWr + OFF(1,l,0);
  const unsigned short* mrd_1 = H + laneRd + OFF(0,3,0) + (q>>1)*kSlot;

  __syncthreads();

  auto super = [&](int n, const unsigned short* ra0, const unsigned short* raS,
                   unsigned short* wa, const unsigned short* ma){
    // ---- 1) W1 load for MLP quad m = n-4 (consumed at bottom of THIS superstep)
    const int m = n - 4;
    FragU WAh0,WAl0,WAh1,WAl1;
    float4 wfa0,wfb0,wfa1,wfb1;
    if (m >= 0 && m < kQ){
      const int off = 64*m + q*8;
      if (PS){
        WAh0.v = *(const bf16x8*)(w1hp + off);
        WAl0.v = *(const bf16x8*)(w1lp + off);
        WAh1.v = *(const bf16x8*)(w1hp + off + 32);
        WAl1.v = *(const bf16x8*)(w1lp + off + 32);
      } else {
        wfa0 = *(const float4*)(w1fp + off);
        wfb0 = *(const float4*)(w1fp + off + 4);
        wfa1 = *(const float4*)(w1fp + off + 32);
        wfb1 = *(const float4*)(w1fp + off + 36);
      }
    }
    const int pr = n - l;                 // this wave's quad
    // ---- 1b) x prefetch for next quad (wave 0)
    float4 xn0,xn1,xn2,xn3;
    if (l==0 && pr+1 < kQ){
      const float* xq = xp + 16*(pr+1);
      xn0 = *(const float4*)(xq+ 0); xn1 = *(const float4*)(xq+ 4);
      xn2 = *(const float4*)(xq+ 8); xn3 = *(const float4*)(xq+12);
    }

    // ---- 2) recurrent layer l, four timesteps of quad pr
    if (pr >= 0 && pr < kQ){
#pragma unroll
      for (int st=0; st<4; ++st){
        // reads: q<2 -> h_{l-1}(4pr+st); q>=2 -> h_l(4pr+st-1)
        // st=0 via ra0; st>=1 via raS + (st-1)*kSlot  (all compile-time imms)
        const unsigned short* rp_ = (st==0) ? ra0 : (raS + (st-1)*kSlot);
        FragU Bh, Bl;
        Bh.v = *(const bf16x8*)(rp_);
        Bl.v = *(const bf16x8*)(rp_ + 16);
        if (l==0){
          const float4 xv = (st==0)?xc0:(st==1)?xc1:(st==2)?xc2:xc3;
          if (q==0){
            const unsigned u0=__float_as_uint(xv.x), u1=__float_as_uint(xv.y);
            const unsigned u2=__float_as_uint(xv.z), u3=__float_as_uint(xv.w);
            Bh.u[0] = (u0>>16)|(u1&0xffff0000u);
            Bh.u[1] = (u2>>16)|(u3&0xffff0000u);
            Bh.u[2] = 0u; Bh.u[3] = 0u;
            const float f0 = xv.x-__uint_as_float(u0&0xffff0000u);
            const float f1 = xv.y-__uint_as_float(u1&0xffff0000u);
            const float f2 = xv.z-__uint_as_float(u2&0xffff0000u);
            const float f3 = xv.w-__uint_as_float(u3&0xffff0000u);
            Bl.u[0] = (__float_as_uint(f0)>>16)|(__float_as_uint(f1)&0xffff0000u);
            Bl.u[1] = (__float_as_uint(f2)>>16)|(__float_as_uint(f3)&0xffff0000u);
            Bl.u[2] = 0u; Bl.u[3] = 0u;
          } else if (q==1){
#pragma unroll
            for (int r=0;r<4;++r){ Bh.u[r]=0u; Bl.u[r]=0u; }
          }
        }

        float si[4], sf[4], sg[4], so[4];
#pragma unroll
        for (int tile=0;tile<4;++tile){
          f32x4 acc = biasf[tile];
          acc = __builtin_amdgcn_mfma_f32_16x16x32_bf16(A[tile][0].v,Bh.v,acc,0,0,0);
          acc = __builtin_amdgcn_mfma_f32_16x16x32_bf16(A[tile][0].v,Bl.v,acc,0,0,0);
          acc = __builtin_amdgcn_mfma_f32_16x16x32_bf16(A[tile][1].v,Bh.v,acc,0,0,0);
#pragma unroll
          for (int r=0;r<4;++r){
            const float a = sig_scaled(acc[r]);
            if      (tile==0) si[r]=a;
            else if (tile==1) sf[r]=a;
            else if (tile==2) sg[r]=fmaf(a,2.f,-1.f);
            else              so[r]=a;
          }
        }
        float hn[4];
#pragma unroll
        for (int r=0;r<4;++r){
          cst[r] = fmaf(sf[r], cst[r], si[r]*sg[r]);
          hn[r] = so[r]*tanh_true(cst[r]);
        }
        // producer-side trunc pack -> interleaved hi/lo row
        {
          const unsigned u0=__float_as_uint(hn[0]), u1=__float_as_uint(hn[1]);
          const unsigned u2=__float_as_uint(hn[2]), u3=__float_as_uint(hn[3]);
          const unsigned hi01 = (u0>>16)|(u1&0xffff0000u);
          const unsigned hi23 = (u2>>16)|(u3&0xffff0000u);
          const float f0 = hn[0]-__uint_as_float(u0&0xffff0000u);
          const float f1 = hn[1]-__uint_as_float(u1&0xffff0000u);
          const float f2 = hn[2]-__uint_as_float(u2&0xffff0000u);
          const float f3 = hn[3]-__uint_as_float(u3&0xffff0000u);
          const unsigned lo01 = (__float_as_uint(f0)>>16)|(__float_as_uint(f1)&0xffff0000u);
          const unsigned lo23 = (__float_as_uint(f2)>>16)|(__float_as_uint(f3)&0xffff0000u);
          *(uint2v*)(wa + st*kSlot)      = (uint2v){hi01,hi23};
          *(uint2v*)(wa + st*kSlot + 16) = (uint2v){lo01,lo23};
        }
      }
    }
    if (l==0 && pr+1 < kQ){ xc0=xn0; xc1=xn1; xc2=xn2; xc3=xn3; }

    // ---- 3) MLP tile wv for quad m: pairs 2m, 2m+1 (K=32 each)
    if (m >= 0 && m < kQ){
#pragma unroll
      for (int pp=0; pp<2; ++pp){
        const unsigned short* bp = ma + pp*(2*kSlot);
        FragU Bh, Bl;
        Bh.v = *(const bf16x8*)(bp);
        Bl.v = *(const bf16x8*)(bp + 16);
        FragU Ah, Al;
        if (PS){
          Ah = pp ? WAh1 : WAh0;
          Al = pp ? WAl1 : WAl0;
        } else {
          const float4 wa4 = pp ? wfa1 : wfa0;
          const float4 wb4 = pp ? wfb1 : wfb0;
          float v[8] = {wa4.x,wa4.y,wa4.z,wa4.w,wb4.x,wb4.y,wb4.z,wb4.w};
          split8(v,Ah,Al);
        }
        mlpacc = __builtin_amdgcn_mfma_f32_16x16x32_bf16(Ah.v,Bh.v,mlpacc,0,0,0);
        mlpacc = __builtin_amdgcn_mfma_f32_16x16x32_bf16(Ah.v,Bl.v,mlpacc,0,0,0);
        mlpacc = __builtin_amdgcn_mfma_f32_16x16x32_bf16(Al.v,Bh.v,mlpacc,0,0,0);
      }
    }
    __syncthreads();
  };

#pragma unroll 1
  for (int n2 = 0; n2 < kSteps/2; ++n2){
    super(2*n2,   ra0_0, raS_0, wrt_0, mrd_0);
    super(2*n2+1, ra0_1, raS_1, wrt_1, mrd_1);
  }

  // ---- epilogue: relu -> ldsR; W2 stage spread over the 4 waves
  {
    f32x4 rv;
#pragma unroll
    for (int r=0;r<4;++r)
      rv[r] = fmaxf(mlpacc[r] + b1[wv*16 + 4*q + r], 0.f);
    *(f32x4*)&ldsR[s][wv*16 + 4*q] = rv;
  }
  __syncthreads();
  {
    const int o  = lane & 31;
    const int oc = (o < kOut) ? o : 0;
    float4 w2r[16];
#pragma unroll
    for (int c2=0;c2<16;++c2) w2r[c2] = *(const float4*)(W2 + oc*64 + 4*c2);
    const float bias2 = b2[oc];
#pragma unroll
    for (int mm=0;mm<2;++mm){
      const int s2 = wv*4 + 2*mm + (lane>>5);
      float a0=bias2, a1=0.f, a2=0.f, a3=0.f;
#pragma unroll
      for (int c2=0;c2<16;++c2){
        const float4 rvv = *(const float4*)&ldsR[s2][4*c2];
        a0 = fmaf(w2r[c2].x, rvv.x, a0);
        a1 = fmaf(w2r[c2].y, rvv.y, a1);
        a2 = fmaf(w2r[c2].z, rvv.z, a2);
        a3 = fmaf(w2r[c2].w, rvv.w, a3);
      }
      if (o < kOut) out[(size_t)(sbase+s2)*kOut + o] = (a0+a1)+(a2+a3);
    }
  }
}

extern "C" void kernel_launch(void* const* d_in, const int* in_sizes, int n_in,
                              void* d_out, int out_size, void* d_ws, size_t ws_size,
                              hipStream_t stream) {
  (void)in_sizes; (void)n_in; (void)out_size;
  const float* x    = (const float*)d_in[0];
  const float* Wih0 = (const float*)d_in[1];
  const float* Wihr = (const float*)d_in[2];
  const float* Whh  = (const float*)d_in[3];
  const float* bih  = (const float*)d_in[4];
  const float* bhh  = (const float*)d_in[5];
  const float* W1   = (const float*)d_in[6];
  const float* b1   = (const float*)d_in[7];
  const float* W2   = (const float*)d_in[8];
  const float* b2   = (const float*)d_in[9];
  float* out = (float*)d_out;

  const size_t splitBytes = (size_t)kW1Elems * sizeof(short) * 2;
  dim3 grid(8192/16), block(256);
  if (ws_size >= splitBytes) {
    short* W1h = (short*)d_ws;
    short* W1l = W1h + kW1Elems;
    hipLaunchKernelGGL(presplit_w1, dim3((kW1Elems+255)/256), dim3(256), 0, stream,
                       W1, W1h, W1l);
    hipLaunchKernelGGL(lstm_pipe<true>, grid, block, 0, stream,
                       x, Wih0, Wihr, Whh, bih, bhh, W1, b1, W2, b2, W1h, W1l, out);
  } else {
    hipLaunchKernelGGL(lstm_pipe<false>, grid, block, 0, stream,
                       x, Wih0, Wihr, Whh, bih, bhh, W1, b1, W2, b2,
                       (const short*)nullptr, (const short*)nullptr, out);
  }
}